// Round 8
// baseline (117.061 us; speedup 1.0000x reference)
//
#include <hip/hip_runtime.h>
#include <math.h>

// Problem constants (fixed by setup_inputs)
constexpr int B       = 2;
constexpr int N       = 32768;
constexpr int D       = 3;
constexpr int M_FULL  = 8192;
constexpr int SUBDIV  = 8;
constexpr int M       = M_FULL / SUBDIV;   // 1024 subsampled verts per (b,d)
constexpr int K       = 512;               // value buckets over [-4,4]
constexpr float LO    = -4.0f;
constexpr float INV_W = 64.0f;             // 1 / (8/512)
constexpr int BLOCK   = 1024;
constexpr int NPAIR   = B * D;             // 6
constexpr int CHUNKS  = N / BLOCK;         // 32 consumer blocks per pair
constexpr int GRID    = NPAIR + NPAIR * CHUNKS;   // 6 builders + 192 consumers = 198 (< 256 CUs)
constexpr float K4    = 5.770780163555852f; // 4*log2(e): e^{4t} = 2^{K4*t}

// ws layout (ints/floats, 4 B units):
//   pair p table: ws[p*8192 .. p*8192+8191]  (mirrors LDS layout below)
//   flag[p]     : ws[6*8192 + 16*p]          (64 B apart, no false sharing)
constexpr int TSTRIDE  = 8192;
constexpr int FLAG_OFF = NPAIR * TSTRIDE;
constexpr unsigned MAGIC = 0x5F3759DFu;     // != 0xAAAAAAAA poison

// LDS mirror layout (floats):
//   [0] sV  [1024] sAp [2048] sSp [3072] sAm [4096] sSm
//   [5120] gAp [5632] gSp [6144] gAm [6656] gSm
//   [7168] beg(int) [7680] cnt(int)   = 8192 floats; +512 builder-only (cur)

// ---- 512-element wave-parallel scans (one wave, lane owns 8 slots) ----
__device__ inline void scan512_pre(float* a) {   // exclusive prefix, small-first
    const int lane = threadIdx.x & 63;
    const int base = lane * 8;
    float xv[8], e[8]; float ls = 0.f;
    #pragma unroll
    for (int t = 0; t < 8; ++t) xv[t] = a[base + t];
    #pragma unroll
    for (int t = 0; t < 8; ++t) { e[t] = ls; ls += xv[t]; }
    float inc = ls;
    #pragma unroll
    for (int off = 1; off < 64; off <<= 1) {
        const float tmp = __shfl_up(inc, off, 64);
        if (lane >= off) inc += tmp;
    }
    const float exoff = inc - ls;
    #pragma unroll
    for (int t = 0; t < 8; ++t) a[base + t] = exoff + e[t];
}

__device__ inline void scan512_suf(float* a) {   // inclusive suffix, small-first
    const int lane = threadIdx.x & 63;
    const int base = lane * 8;
    float xv[8], e[8]; float ls = 0.f;
    #pragma unroll
    for (int t = 0; t < 8; ++t) xv[t] = a[base + t];
    #pragma unroll
    for (int t = 7; t >= 0; --t) { e[t] = ls; ls += xv[t]; }
    float inc = ls;
    #pragma unroll
    for (int off = 1; off < 64; off <<= 1) {
        const float tmp = __shfl_down(inc, off, 64);
        if (lane + off < 64) inc += tmp;
    }
    const float exoff = inc - ls;
    #pragma unroll
    for (int t = 0; t < 8; ++t) a[base + t] = exoff + e[t] + xv[t];
}

__device__ inline void scan512_i(const int* cntA, int* begA, int* curA) {
    const int lane = threadIdx.x & 63;
    const int base = lane * 8;
    int xv[8], e[8]; int ls = 0;
    #pragma unroll
    for (int t = 0; t < 8; ++t) xv[t] = cntA[base + t];
    #pragma unroll
    for (int t = 0; t < 8; ++t) { e[t] = ls; ls += xv[t]; }
    int inc = ls;
    #pragma unroll
    for (int off = 1; off < 64; off <<= 1) {
        const int tmp = __shfl_up(inc, off, 64);
        if (lane >= off) inc += tmp;
    }
    const int exoff = inc - ls;
    #pragma unroll
    for (int t = 0; t < 8; ++t) {
        begA[base + t] = exoff + e[t];
        curA[base + t] = exoff + e[t];
    }
}

__global__ __launch_bounds__(BLOCK) void deformer_pc(
    const float* __restrict__ x,
    const float* __restrict__ dverts,
    const float* __restrict__ mverts,
    float* __restrict__ out,
    unsigned* __restrict__ ws)
{
    __shared__ __align__(16) float lds[TSTRIDE + K];   // 34 KB
    float* sV  = lds;          float* sAp = lds + 1024;
    float* sSp = lds + 2048;   float* sAm = lds + 3072;
    float* sSm = lds + 4096;
    float* gAp = lds + 5120;   float* gSp = lds + 5632;
    float* gAm = lds + 6144;   float* gSm = lds + 6656;
    int*   beg = (int*)(lds + 7168);
    int*   cnt = (int*)(lds + 7680);
    int*   cur = (int*)(lds + TSTRIDE);   // builder-only scratch

    const int tid = threadIdx.x;

    if (blockIdx.x < NPAIR) {
        // ================= BUILDER: one block per pair =================
        const int p = blockIdx.x;
        const int b = p / 3, d = p % 3;

        if (tid < K) {
            cnt[tid] = 0; gAp[tid] = 0.f; gSp[tid] = 0.f;
            gAm[tid] = 0.f; gSm[tid] = 0.f;
        }
        __syncthreads();

        // one vert per thread (M == BLOCK)
        const int g = (b * M_FULL + tid * SUBDIV) * D + d;
        const float v = dverts[g];
        const float w = mverts[g];
        const float epv = __builtin_amdgcn_exp2f( K4 * v);   // e^{4v}
        const float emv = __builtin_amdgcn_exp2f(-K4 * v);   // e^{-4v}
        const float ap = w * epv, sp = epv;
        const float am = w * emv, sm = emv;
        int bj = (int)floorf((v - LO) * INV_W);
        bj = bj < 0 ? 0 : (bj > K - 1 ? K - 1 : bj);
        atomicAdd(&cnt[bj], 1);
        atomicAdd(&gAp[bj], ap);
        atomicAdd(&gSp[bj], sp);
        atomicAdd(&gAm[bj], am);
        atomicAdd(&gSm[bj], sm);
        __syncthreads();

        const int wid = tid >> 6;
        if      (wid == 0) scan512_i(cnt, beg, cur);
        else if (wid == 1) scan512_pre(gAp);
        else if (wid == 2) scan512_pre(gSp);
        else if (wid == 3) scan512_suf(gAm);
        else if (wid == 4) scan512_suf(gSm);
        __syncthreads();

        const int pos = atomicAdd(&cur[bj], 1);
        sV[pos] = v; sAp[pos] = ap; sSp[pos] = sp;
        sAm[pos] = am; sSm[pos] = sm;
        __syncthreads();

        // publish: 8192 words = 2048 int4, coalesced, bit-preserving
        int4* tp = reinterpret_cast<int4*>(ws + p * TSTRIDE);
        const int4* lp = reinterpret_cast<const int4*>(lds);
        tp[tid]        = lp[tid];
        tp[tid + 1024] = lp[tid + 1024];
        __threadfence();   // drain stores to coherence point
        __syncthreads();
        if (tid == 0)
            __hip_atomic_store(&ws[FLAG_OFF + 16 * p], MAGIC,
                               __ATOMIC_RELEASE, __HIP_MEMORY_SCOPE_AGENT);
        return;
    }

    // ================= CONSUMER: 32 blocks per pair =================
    const int idx = blockIdx.x - NPAIR;
    const int p = idx >> 5;           // pair 0..5
    const int c = idx & 31;           // chunk within pair
    const int b = p / 3, d = p % 3;

    if (tid == 0) {
        while (__hip_atomic_load(&ws[FLAG_OFF + 16 * p],
                                 __ATOMIC_ACQUIRE, __HIP_MEMORY_SCOPE_AGENT)
               != MAGIC)
            __builtin_amdgcn_s_sleep(2);
    }
    __syncthreads();

    {   // bulk-load the pair's table into LDS
        const int4* tp = reinterpret_cast<const int4*>(ws + p * TSTRIDE);
        int4* lp = reinterpret_cast<int4*>(lds);
        lp[tid]        = tp[tid];
        lp[tid + 1024] = tp[tid + 1024];
    }
    __syncthreads();

    // ---- Query: one output element per thread ----
    const int n = c * BLOCK + tid;
    const int o = (b * N + n) * D + d;
    const float xq = x[o];

    int j = (int)floorf((xq - LO) * INV_W);
    j = j < 0 ? 0 : (j > K - 1 ? K - 1 : j);

    const float en  = __builtin_amdgcn_exp2f(-K4 * xq);  // e^{-4x}
    const float epx = __builtin_amdgcn_exp2f( K4 * xq);  // e^{+4x}

    const float Ap = gAp[j];                          // buckets strictly below j
    const float Sp = gSp[j];
    const float Am = (j < K - 1) ? gAm[j + 1] : 0.f;  // buckets strictly above j
    const float Sm = (j < K - 1) ? gSm[j + 1] : 0.f;

    const int s0 = beg[j], s1 = s0 + cnt[j];
    float rAp = 0.f, rSp = 0.f, rAm = 0.f, rSm = 0.f;
    for (int i = s0; i < s1; ++i) {
        const bool le = (sV[i] <= xq);
        rAp += le ? sAp[i] : 0.f;
        rSp += le ? sSp[i] : 0.f;
        rAm += le ? 0.f : sAm[i];
        rSm += le ? 0.f : sSm[i];
    }
    out[o] = (en * (Ap + rAp) + epx * (Am + rAm)) /
             (en * (Sp + rSp) + epx * (Sm + rSm));
}

extern "C" void kernel_launch(void* const* d_in, const int* in_sizes, int n_in,
                              void* d_out, int out_size, void* d_ws, size_t ws_size,
                              hipStream_t stream) {
    const float* x  = (const float*)d_in[0];
    const float* dv = (const float*)d_in[1];
    const float* mv = (const float*)d_in[2];
    float* out = (float*)d_out;
    unsigned* ws = (unsigned*)d_ws;   // ~192.4 KB used; poison 0xAA.. != MAGIC

    deformer_pc<<<GRID, BLOCK, 0, stream>>>(x, dv, mv, out, ws);
}

// Round 9
// 68.413 us; speedup vs baseline: 1.7111x; 1.7111x over previous
//
#include <hip/hip_runtime.h>
#include <math.h>

// Problem constants (fixed by setup_inputs)
constexpr int B       = 2;
constexpr int N       = 32768;
constexpr int D       = 3;
constexpr int M_FULL  = 8192;
constexpr int SUBDIV  = 8;
constexpr int M       = M_FULL / SUBDIV;   // 1024 subsampled verts per (b,d)
constexpr int K       = 512;               // value buckets over [-4,4]
constexpr float LO    = -4.0f;
constexpr float INV_W = 64.0f;             // 1 / (8/512)
constexpr int BLOCK   = 1024;              // 16 waves/CU
constexpr int CHUNKS  = N / BLOCK;         // 32 blocks per (b,d) pair
constexpr int GRID    = B * D * CHUNKS;    // 192 blocks -> 1 per CU
constexpr float K4    = 5.770780163555852f; // 4*log2(e): e^{4t} = 2^{K4*t}

// ---- 512-element wave-parallel scans (one wave, lane owns 8 slots) ----
__device__ inline void scan512_pre(float* a) {   // exclusive prefix, small-first
    const int lane = threadIdx.x & 63;
    const int base = lane * 8;
    float xv[8], e[8]; float ls = 0.f;
    #pragma unroll
    for (int t = 0; t < 8; ++t) xv[t] = a[base + t];
    #pragma unroll
    for (int t = 0; t < 8; ++t) { e[t] = ls; ls += xv[t]; }
    float inc = ls;
    #pragma unroll
    for (int off = 1; off < 64; off <<= 1) {
        const float tmp = __shfl_up(inc, off, 64);
        if (lane >= off) inc += tmp;
    }
    const float exoff = inc - ls;
    #pragma unroll
    for (int t = 0; t < 8; ++t) a[base + t] = exoff + e[t];
}

__device__ inline void scan512_suf(float* a) {   // inclusive suffix, small-first
    const int lane = threadIdx.x & 63;
    const int base = lane * 8;
    float xv[8], e[8]; float ls = 0.f;
    #pragma unroll
    for (int t = 0; t < 8; ++t) xv[t] = a[base + t];
    #pragma unroll
    for (int t = 7; t >= 0; --t) { e[t] = ls; ls += xv[t]; }
    float inc = ls;
    #pragma unroll
    for (int off = 1; off < 64; off <<= 1) {
        const float tmp = __shfl_down(inc, off, 64);
        if (lane + off < 64) inc += tmp;
    }
    const float exoff = inc - ls;
    #pragma unroll
    for (int t = 0; t < 8; ++t) a[base + t] = exoff + e[t] + xv[t];
}

__device__ inline void scan512_beg(const int* cntA, int* begA) {  // exclusive
    const int lane = threadIdx.x & 63;
    const int base = lane * 8;
    int xv[8], e[8]; int ls = 0;
    #pragma unroll
    for (int t = 0; t < 8; ++t) xv[t] = cntA[base + t];
    #pragma unroll
    for (int t = 0; t < 8; ++t) { e[t] = ls; ls += xv[t]; }
    int inc = ls;
    #pragma unroll
    for (int off = 1; off < 64; off <<= 1) {
        const int tmp = __shfl_up(inc, off, 64);
        if (lane >= off) inc += tmp;
    }
    const int exoff = inc - ls;
    #pragma unroll
    for (int t = 0; t < 8; ++t) begA[base + t] = exoff + e[t];
}

__global__ __launch_bounds__(BLOCK) void deformer_one(
    const float* __restrict__ x,
    const float* __restrict__ dverts,
    const float* __restrict__ mverts,
    float* __restrict__ out)
{
    // bucket-grouped per-vert tuples
    __shared__ float sV[M], sAp[M], sSp[M], sAm[M], sSm[M];      // 20 KB
    // per-bucket aggregates; after scans: Ap/Sp = exclusive prefix,
    // Am/Sm = inclusive suffix (both accumulated tiny-terms-first).
    __shared__ float gAp[K], gSp[K], gAm[K], gSm[K];             // 8 KB
    __shared__ int   cnt[K], beg[K];                              // 4 KB

    const int tid = threadIdx.x;
    const int p = blockIdx.x >> 5;    // pair 0..5
    const int c = blockIdx.x & 31;    // chunk within pair
    const int b = p / 3, d = p % 3;

    // ---- Issue ALL global loads up front (dv, mv, x independent) ----
    const int g = (b * M_FULL + tid * SUBDIV) * D + d;
    const float v = dverts[g];
    const float w = mverts[g];
    const int n = c * BLOCK + tid;
    const int o = (b * N + n) * D + d;
    const float xq = x[o];            // query input prefetched under build

    // zero-init overlaps the load drain
    if (tid < K) {
        cnt[tid] = 0; gAp[tid] = 0.f; gSp[tid] = 0.f;
        gAm[tid] = 0.f; gSm[tid] = 0.f;
    }

    // per-vert terms (stall on v/w here, not earlier)
    const float epv = __builtin_amdgcn_exp2f( K4 * v);   // e^{4v}
    const float emv = __builtin_amdgcn_exp2f(-K4 * v);   // e^{-4v}
    const float ap = w * epv, sp = epv;
    const float am = w * emv, sm = emv;
    int bj = (int)floorf((v - LO) * INV_W);
    bj = bj < 0 ? 0 : (bj > K - 1 ? K - 1 : bj);
    __syncthreads();                  // zero-init visible

    // rank captured from the cnt atomic: in-bucket slot, no second atomic pass
    const int rank = atomicAdd(&cnt[bj], 1);
    atomicAdd(&gAp[bj], ap);
    atomicAdd(&gSp[bj], sp);
    atomicAdd(&gAm[bj], am);
    atomicAdd(&gSm[bj], sm);
    __syncthreads();

    // Scans: 5 scans on 5 separate waves, concurrent (waves 5-15 fall through).
    const int wid = tid >> 6;
    if      (wid == 0) scan512_beg(cnt, beg);
    else if (wid == 1) scan512_pre(gAp);
    else if (wid == 2) scan512_pre(gSp);
    else if (wid == 3) scan512_suf(gAm);
    else if (wid == 4) scan512_suf(gSm);
    __syncthreads();

    // Scatter into bucket-grouped order at precomputed slot.
    const int pos = beg[bj] + rank;
    sV[pos] = v; sAp[pos] = ap; sSp[pos] = sp;
    sAm[pos] = am; sSm[pos] = sm;
    __syncthreads();

    // ---- Query: one output element per thread (xq already in register) ----
    int j = (int)floorf((xq - LO) * INV_W);
    j = j < 0 ? 0 : (j > K - 1 ? K - 1 : j);

    const float en  = __builtin_amdgcn_exp2f(-K4 * xq);  // e^{-4x}
    const float epx = __builtin_amdgcn_exp2f( K4 * xq);  // e^{+4x}

    const float Ap = gAp[j];                          // buckets strictly below j
    const float Sp = gSp[j];
    const float Am = (j < K - 1) ? gAm[j + 1] : 0.f;  // buckets strictly above j
    const float Sm = (j < K - 1) ? gSm[j + 1] : 0.f;

    const int s0 = beg[j], s1 = s0 + cnt[j];
    float rAp = 0.f, rSp = 0.f, rAm = 0.f, rSm = 0.f;
    for (int i = s0; i < s1; ++i) {
        const bool le = (sV[i] <= xq);
        rAp += le ? sAp[i] : 0.f;
        rSp += le ? sSp[i] : 0.f;
        rAm += le ? 0.f : sAm[i];
        rSm += le ? 0.f : sSm[i];
    }
    out[o] = (en * (Ap + rAp) + epx * (Am + rAm)) /
             (en * (Sp + rSp) + epx * (Sm + rSm));
}

extern "C" void kernel_launch(void* const* d_in, const int* in_sizes, int n_in,
                              void* d_out, int out_size, void* d_ws, size_t ws_size,
                              hipStream_t stream) {
    const float* x  = (const float*)d_in[0];
    const float* dv = (const float*)d_in[1];
    const float* mv = (const float*)d_in[2];
    float* out = (float*)d_out;

    deformer_one<<<GRID, BLOCK, 0, stream>>>(x, dv, mv, out);
}